// Round 11
// baseline (4396.982 us; speedup 1.0000x reference)
//
#include <hip/hip_runtime.h>
#include <cstddef>

#define NB   256   // batch
#define TT   300   // timesteps
#define SS   150   // input feature dim
#define HH   100   // hidden
#define G4   400   // 4*H gates
#define NCLS 60
#define NW   832   // 13 waves per recurrence block

__device__ __forceinline__ float sigf(float x) {
    float e = __expf(-x);
    return 1.f / (1.f + e);
}
__device__ __forceinline__ float tanh_fast(float x) {
    float e = __expf(2.f * x);
    return 1.f - 2.f / (e + 1.f);
}
__device__ __forceinline__ float shflx(float v, int m) {
    return __shfl_xor(v, m, 64);
}

// ---------------------------------------------------------------------------
// GEMM: C[M x 400] = A[M x K] * W[400 x K]^T + (bih + bhh)   (unchanged)
// ---------------------------------------------------------------------------
template<int K>
__global__ __launch_bounds__(256, 2) void gemm_inproj(
    const float* __restrict__ A, const float* __restrict__ W,
    const float* __restrict__ bih, const float* __restrict__ bhh,
    float* __restrict__ C)
{
    __shared__ float As[K][64];
    __shared__ float Bs[K][64];
    const int m0 = blockIdx.x * 64;
    const int n0 = blockIdx.y * 64;
    const int tid = threadIdx.x;
    const int r = tid & 63;
    constexpr int K2 = K / 2;

    for (int i = tid; i < 64 * K2; i += 256) {
        int c2 = i >> 6;
        float2 v = *(const float2*)(A + (size_t)(m0 + r) * K + 2 * c2);
        As[2 * c2][r] = v.x;
        As[2 * c2 + 1][r] = v.y;
    }
    {
        int g = n0 + r;
        if (g < G4) {
            for (int i = tid; i < 64 * K2; i += 256) {
                int c2 = i >> 6;
                float2 v = *(const float2*)(W + (size_t)g * K + 2 * c2);
                Bs[2 * c2][r] = v.x;
                Bs[2 * c2 + 1][r] = v.y;
            }
        } else {
            for (int i = tid; i < 64 * K2; i += 256) {
                int c2 = i >> 6;
                Bs[2 * c2][r] = 0.f;
                Bs[2 * c2 + 1][r] = 0.f;
            }
        }
    }
    __syncthreads();

    const int tx = tid & 15, ty = tid >> 4;
    float acc[4][4] = {};
#pragma unroll 10
    for (int k = 0; k < K; ++k) {
        float4 a = *(const float4*)&As[k][ty * 4];
        float4 b = *(const float4*)&Bs[k][tx * 4];
        acc[0][0] += a.x * b.x; acc[0][1] += a.x * b.y; acc[0][2] += a.x * b.z; acc[0][3] += a.x * b.w;
        acc[1][0] += a.y * b.x; acc[1][1] += a.y * b.y; acc[1][2] += a.y * b.z; acc[1][3] += a.y * b.w;
        acc[2][0] += a.z * b.x; acc[2][1] += a.z * b.y; acc[2][2] += a.z * b.z; acc[2][3] += a.z * b.w;
        acc[3][0] += a.w * b.x; acc[3][1] += a.w * b.y; acc[3][2] += a.w * b.z; acc[3][3] += a.w * b.w;
    }

    const int g0 = n0 + tx * 4;
    if (g0 + 3 < G4) {
        float b0 = bih[g0] + bhh[g0];
        float b1 = bih[g0 + 1] + bhh[g0 + 1];
        float b2 = bih[g0 + 2] + bhh[g0 + 2];
        float b3 = bih[g0 + 3] + bhh[g0 + 3];
#pragma unroll
        for (int i = 0; i < 4; ++i) {
            float4 o;
            o.x = acc[i][0] + b0; o.y = acc[i][1] + b1;
            o.z = acc[i][2] + b2; o.w = acc[i][3] + b3;
            *(float4*)(C + (size_t)(m0 + ty * 4 + i) * G4 + g0) = o;
        }
    }
}

// ---------------------------------------------------------------------------
// LSTM recurrence v3: LDS weights + quad-shuffle gate gather, ONE barrier/step.
// 832 threads (13 waves). Worker tid<800: u=tid>>3 (unit), q=tid&3 (gate),
// kh=(tid>>2)&1 (k-half). Thread computes 52 MACs of row q*100+u over
// k in [52*kh, 52*kh+52) (kh=1 tail covered by zero pads). Combine:
//   gate = part + shfl_xor(part,4)        (k halves)
//   3x shfl_xor(1/2) gathers all 4 gates into every lane of the quad;
// all 8 lanes of a unit compute identical (c,h); lane r==0 writes h.
// h double-buffered in LDS -> single __syncthreads per step (no race).
// Weight ds_reads re-issued per step via opaque zero offset (no hoist/spill).
// MODE 0: rot+tr (512 blocks); per-step fc(H->3) runs on spare lanes
// tid>=800 overlapped with matvec. MODE 1: write h seq. MODE 2: mean+fc+sm.
// ---------------------------------------------------------------------------
template<int MODE>
__global__ __launch_bounds__(NW) void lstm_rec(
    const float* __restrict__ xgA, const float* __restrict__ xgB,
    const float* __restrict__ WhhA, const float* __restrict__ WhhB,
    const float* __restrict__ fwA, const float* __restrict__ fbA,
    const float* __restrict__ fwB, const float* __restrict__ fbB,
    float* __restrict__ oA, float* __restrict__ oB)
{
    __shared__ float wlds[G4 * HH + 4];   // 160,016 B (+4 pad for row-399 tail)
    __shared__ float h_lds[2][104];       // double-buffered h, zero-padded
    __shared__ float fcw[3 * HH + 4];     // MODE0 fc weights

    const int tid = threadIdx.x;
    int n = blockIdx.x;
    const float* xg = xgA;
    const float* whh = WhhA;
    const float* fw = fwA;
    const float* fb = fbA;
    float* op = oA;
    if (MODE == 0 && blockIdx.x >= NB) {
        n = blockIdx.x - NB;
        xg = xgB; whh = WhhB; fw = fwB; fb = fbB; op = oB;
    }

    // ---- stage Whh into LDS
    {
        const float4* src = (const float4*)whh;
        float4* dst = (float4*)wlds;
        for (int i = tid; i < G4 * HH / 4; i += NW) dst[i] = src[i];
    }
    if (tid < 4) wlds[G4 * HH + tid] = 0.f;
    if (tid < 208) ((float*)h_lds)[tid] = 0.f;   // both buffers + pads
    if (MODE == 0) {
        for (int i = tid; i < 3 * HH; i += NW) fcw[i] = fw[i];
        if (tid < 3) fcw[3 * HH + tid] = fb[tid];
    }
    __syncthreads();

    const bool worker = (tid < 800);
    const int u  = tid >> 3;
    const int q  = tid & 3;
    const int kh = (tid >> 2) & 1;
    const int row = q * HH + (worker ? u : 0);
    const int k0 = kh * 52;
    const float4* wrow = (const float4*)(wlds + row * HH + k0);

    const bool isx = worker && (kh == 0);
    const float* xgn = xg + (size_t)n * TT * G4 + row;
    float x0 = 0.f, x1 = 0.f;
    if (isx) { x0 = xgn[0]; x1 = xgn[G4]; }

    float c = 0.f, hsum = 0.f;

    for (int t = 0; t < TT; ++t) {
        const int p = t & 1;             // read buffer (holds h_{t-1})

        if (MODE == 0 && tid >= 800 && t > 0) {
            // fc of h_{t-1}, on spare lanes (wave 12, lanes 32-63),
            // overlapped with the matvec; reads the same (stable) buffer.
            const int l = tid - 800;     // 0..31
            float p0 = 0.f, p1 = 0.f, p2 = 0.f;
            for (int k = l; k < HH; k += 32) {
                float hk = h_lds[p][k];
                p0 += hk * fcw[k];
                p1 += hk * fcw[HH + k];
                p2 += hk * fcw[2 * HH + k];
            }
#pragma unroll
            for (int s = 16; s; s >>= 1) {
                p0 += shflx(p0, s); p1 += shflx(p1, s); p2 += shflx(p2, s);
            }
            if (l == 0) {
                size_t o = ((size_t)n * TT + (t - 1)) * 3;
                op[o] = p0 + fcw[300];
                op[o + 1] = p1 + fcw[301];
                op[o + 2] = p2 + fcw[302];
            }
        }

        if (worker) {
            float s0 = isx ? x0 : 0.f;
            float s1 = 0.f, s2 = 0.f, s3 = 0.f;
            x0 = x1;
            if (isx && t + 2 < TT) x1 = xgn[(size_t)(t + 2) * G4];

            // opaque zero so weight reads can't be hoisted (R5/R7 lesson)
            int z = t;
            asm volatile("" : "+v"(z));
            const float4* wrt = wrow + (z - t);
            const float4* hseg = (const float4*)(&h_lds[p][0] + k0);
#pragma unroll
            for (int j = 0; j < 13; ++j) {
                float4 wv = wrt[j];
                float4 hv = hseg[j];   // kh=1, j=12 reads zero pad -> exact 0
                switch (j & 3) {
                case 0: s0 = fmaf(hv.x, wv.x, fmaf(hv.y, wv.y, fmaf(hv.z, wv.z, fmaf(hv.w, wv.w, s0)))); break;
                case 1: s1 = fmaf(hv.x, wv.x, fmaf(hv.y, wv.y, fmaf(hv.z, wv.z, fmaf(hv.w, wv.w, s1)))); break;
                case 2: s2 = fmaf(hv.x, wv.x, fmaf(hv.y, wv.y, fmaf(hv.z, wv.z, fmaf(hv.w, wv.w, s2)))); break;
                default: s3 = fmaf(hv.x, wv.x, fmaf(hv.y, wv.y, fmaf(hv.z, wv.z, fmaf(hv.w, wv.w, s3)))); break;
                }
            }
            float part = (s0 + s1) + (s2 + s3);
            float gate = part + shflx(part, 4);        // combine k halves
            float g1  = shflx(gate, 1);
            float g2v = shflx(gate, 2);
            float g3  = shflx(g1, 2);
            // gate value for target type t sits at m = q ^ t
            float gi = (q == 0) ? gate : (q == 1) ? g1 : (q == 2) ? g2v : g3;
            float gf = (q == 1) ? gate : (q == 0) ? g1 : (q == 3) ? g2v : g3;
            float gg = (q == 2) ? gate : (q == 3) ? g1 : (q == 0) ? g2v : g3;
            float go = (q == 3) ? gate : (q == 2) ? g1 : (q == 1) ? g2v : g3;

            c = sigf(gf) * c + sigf(gi) * tanh_fast(gg);
            float h = sigf(go) * tanh_fast(c);
            if ((tid & 7) == 0) {
                h_lds[p ^ 1][u] = h;
                if (MODE == 1) op[((size_t)n * TT + t) * HH + u] = h;
                if (MODE == 2) hsum += h;
            }
        }
        __syncthreads();
    }

    if (MODE == 0 && tid >= 800) {
        // fc of the final h_{TT-1} (in h_lds[TT & 1])
        const int l = tid - 800;
        float p0 = 0.f, p1 = 0.f, p2 = 0.f;
        for (int k = l; k < HH; k += 32) {
            float hk = h_lds[TT & 1][k];
            p0 += hk * fcw[k];
            p1 += hk * fcw[HH + k];
            p2 += hk * fcw[2 * HH + k];
        }
#pragma unroll
        for (int s = 16; s; s >>= 1) {
            p0 += shflx(p0, s); p1 += shflx(p1, s); p2 += shflx(p2, s);
        }
        if (l == 0) {
            size_t o = ((size_t)n * TT + (TT - 1)) * 3;
            op[o] = p0 + fcw[300];
            op[o + 1] = p1 + fcw[301];
            op[o + 2] = p2 + fcw[302];
        }
    }

    if (MODE == 2) {
        if (worker && (tid & 7) == 0) h_lds[0][u] = hsum * (1.f / TT);
        __syncthreads();
        if (tid < 64) {
            float logit = -3.0e38f;
            if (tid < NCLS) {
                float a = fb[tid];          // fc weights from global (L2-hot)
                const float* fr = fw + tid * HH;
#pragma unroll 10
                for (int k = 0; k < HH; ++k) a += h_lds[0][k] * fr[k];
                logit = a;
            }
            float mx = logit;
#pragma unroll
            for (int s = 32; s; s >>= 1) mx = fmaxf(mx, shflx(mx, s));
            float e = (tid < NCLS) ? __expf(logit - mx) : 0.f;
            float sum = e;
#pragma unroll
            for (int s = 32; s; s >>= 1) sum += shflx(sum, s);
            if (tid < NCLS) op[(size_t)n * NCLS + tid] = e / sum;
        }
    }
}

// ---------------------------------------------------------------------------
// Rotation/translation transform (unchanged)
// ---------------------------------------------------------------------------
__global__ __launch_bounds__(256) void transform_pts(
    const float* __restrict__ x, const float* __restrict__ rot,
    const float* __restrict__ tr, float* __restrict__ xr)
{
    const int idx = blockIdx.x * 4 + (threadIdx.x >> 6);
    const int lane = threadIdx.x & 63;
    const float* ang = rot + (size_t)idx * 3;
    float a = ang[0], b = ang[1], cg = ang[2];
    float ca = cosf(a), sa = sinf(a);
    float cb = cosf(b), sb = sinf(b);
    float cc = cosf(cg), sc = sinf(cg);
    float R00 = cc * cb, R01 = cc * sb * sa + sc * ca, R02 = -cc * sb * ca + sc * sa;
    float R10 = -sc * cb, R11 = -sc * sb * sa + cc * ca, R12 = sc * sb * ca + cc * sa;
    float R20 = sb, R21 = -cb * sa, R22 = cb * ca;
    float t0 = tr[(size_t)idx * 3], t1 = tr[(size_t)idx * 3 + 1], t2 = tr[(size_t)idx * 3 + 2];
    if (lane < 50) {
        const float* xp = x + (size_t)idx * SS + lane * 3;
        float p0 = xp[0] - t0, p1 = xp[1] - t1, p2 = xp[2] - t2;
        float* o = xr + (size_t)idx * SS + lane * 3;
        o[0] = R00 * p0 + R01 * p1 + R02 * p2;
        o[1] = R10 * p0 + R11 * p1 + R12 * p2;
        o[2] = R20 * p0 + R21 * p1 + R22 * p2;
    }
}

// ---------------------------------------------------------------------------
extern "C" void kernel_launch(void* const* d_in, const int* in_sizes, int n_in,
                              void* d_out, int out_size, void* d_ws, size_t ws_size,
                              hipStream_t stream)
{
    const float* x       = (const float*)d_in[0];
    const float* rot_Wih = (const float*)d_in[1];
    const float* rot_Whh = (const float*)d_in[2];
    const float* rot_bih = (const float*)d_in[3];
    const float* rot_bhh = (const float*)d_in[4];
    const float* tr_Wih  = (const float*)d_in[5];
    const float* tr_Whh  = (const float*)d_in[6];
    const float* tr_bih  = (const float*)d_in[7];
    const float* tr_bhh  = (const float*)d_in[8];
    const float* rot_fcW = (const float*)d_in[9];
    const float* rot_fcb = (const float*)d_in[10];
    const float* tr_fcW  = (const float*)d_in[11];
    const float* tr_fcb  = (const float*)d_in[12];
    const float* W0 = (const float*)d_in[13];
    const float* U0 = (const float*)d_in[14];
    const float* b0i = (const float*)d_in[15];
    const float* b0h = (const float*)d_in[16];
    const float* W1 = (const float*)d_in[17];
    const float* U1 = (const float*)d_in[18];
    const float* b1i = (const float*)d_in[19];
    const float* b1h = (const float*)d_in[20];
    const float* W2 = (const float*)d_in[21];
    const float* U2 = (const float*)d_in[22];
    const float* b2i = (const float*)d_in[23];
    const float* b2h = (const float*)d_in[24];
    const float* fcW = (const float*)d_in[25];
    const float* fcb = (const float*)d_in[26];
    float* out = (float*)d_out;

    float* ws = (float*)d_ws;
    float* xgA  = ws;
    float* xgB  = ws + 30720000ull;
    float* rotA = ws + 61440000ull;
    float* trO  = ws + 61670400ull;
    float* xr = xgA;
    float* h0 = xgA + 11520000ull;
    float* h1 = xgA + 19200000ull;

    dim3 gg(1200, 7), bb(256);
    gemm_inproj<150><<<gg, bb, 0, stream>>>(x, rot_Wih, rot_bih, rot_bhh, xgA);
    gemm_inproj<150><<<gg, bb, 0, stream>>>(x, tr_Wih, tr_bih, tr_bhh, xgB);
    lstm_rec<0><<<512, NW, 0, stream>>>(xgA, xgB, rot_Whh, tr_Whh,
                                        rot_fcW, rot_fcb, tr_fcW, tr_fcb,
                                        rotA, trO);
    transform_pts<<<19200, 256, 0, stream>>>(x, rotA, trO, xr);
    gemm_inproj<150><<<gg, bb, 0, stream>>>(xr, W0, b0i, b0h, xgB);
    lstm_rec<1><<<256, NW, 0, stream>>>(xgB, nullptr, U0, nullptr,
                                        nullptr, nullptr, nullptr, nullptr,
                                        h0, nullptr);
    gemm_inproj<100><<<gg, bb, 0, stream>>>(h0, W1, b1i, b1h, xgB);
    lstm_rec<1><<<256, NW, 0, stream>>>(xgB, nullptr, U1, nullptr,
                                        nullptr, nullptr, nullptr, nullptr,
                                        h1, nullptr);
    gemm_inproj<100><<<gg, bb, 0, stream>>>(h1, W2, b2i, b2h, xgB);
    lstm_rec<2><<<256, NW, 0, stream>>>(xgB, nullptr, U2, nullptr,
                                        fcW, fcb, nullptr, nullptr,
                                        out, nullptr);
}

// Round 12
// 3541.496 us; speedup vs baseline: 1.2416x; 1.2416x over previous
//
#include <hip/hip_runtime.h>
#include <cstddef>

#define NB   256   // batch
#define TT   300   // timesteps
#define SS   150   // input feature dim
#define HH   100   // hidden
#define G4   400   // 4*H gates
#define NCLS 60
#define NW   896   // 14 waves per recurrence block

__device__ __forceinline__ float sigf(float x) {
    float e = __expf(-x);
    return 1.f / (1.f + e);
}
__device__ __forceinline__ float tanh_fast(float x) {
    float e = __expf(2.f * x);
    return 1.f - 2.f / (e + 1.f);
}
__device__ __forceinline__ float shflx(float v, int m) {
    return __shfl_xor(v, m, 64);
}

// ---------------------------------------------------------------------------
// GEMM: C[M x 400] = A[M x K] * W[400 x K]^T + (bih + bhh)   (unchanged)
// ---------------------------------------------------------------------------
template<int K>
__global__ __launch_bounds__(256, 2) void gemm_inproj(
    const float* __restrict__ A, const float* __restrict__ W,
    const float* __restrict__ bih, const float* __restrict__ bhh,
    float* __restrict__ C)
{
    __shared__ float As[K][64];
    __shared__ float Bs[K][64];
    const int m0 = blockIdx.x * 64;
    const int n0 = blockIdx.y * 64;
    const int tid = threadIdx.x;
    const int r = tid & 63;
    constexpr int K2 = K / 2;

    for (int i = tid; i < 64 * K2; i += 256) {
        int c2 = i >> 6;
        float2 v = *(const float2*)(A + (size_t)(m0 + r) * K + 2 * c2);
        As[2 * c2][r] = v.x;
        As[2 * c2 + 1][r] = v.y;
    }
    {
        int g = n0 + r;
        if (g < G4) {
            for (int i = tid; i < 64 * K2; i += 256) {
                int c2 = i >> 6;
                float2 v = *(const float2*)(W + (size_t)g * K + 2 * c2);
                Bs[2 * c2][r] = v.x;
                Bs[2 * c2 + 1][r] = v.y;
            }
        } else {
            for (int i = tid; i < 64 * K2; i += 256) {
                int c2 = i >> 6;
                Bs[2 * c2][r] = 0.f;
                Bs[2 * c2 + 1][r] = 0.f;
            }
        }
    }
    __syncthreads();

    const int tx = tid & 15, ty = tid >> 4;
    float acc[4][4] = {};
#pragma unroll 10
    for (int k = 0; k < K; ++k) {
        float4 a = *(const float4*)&As[k][ty * 4];
        float4 b = *(const float4*)&Bs[k][tx * 4];
        acc[0][0] += a.x * b.x; acc[0][1] += a.x * b.y; acc[0][2] += a.x * b.z; acc[0][3] += a.x * b.w;
        acc[1][0] += a.y * b.x; acc[1][1] += a.y * b.y; acc[1][2] += a.y * b.z; acc[1][3] += a.y * b.w;
        acc[2][0] += a.z * b.x; acc[2][1] += a.z * b.y; acc[2][2] += a.z * b.z; acc[2][3] += a.z * b.w;
        acc[3][0] += a.w * b.x; acc[3][1] += a.w * b.y; acc[3][2] += a.w * b.z; acc[3][3] += a.w * b.w;
    }

    const int g0 = n0 + tx * 4;
    if (g0 + 3 < G4) {
        float b0 = bih[g0] + bhh[g0];
        float b1 = bih[g0 + 1] + bhh[g0 + 1];
        float b2 = bih[g0 + 2] + bhh[g0 + 2];
        float b3 = bih[g0 + 3] + bhh[g0 + 3];
#pragma unroll
        for (int i = 0; i < 4; ++i) {
            float4 o;
            o.x = acc[i][0] + b0; o.y = acc[i][1] + b1;
            o.z = acc[i][2] + b2; o.w = acc[i][3] + b3;
            *(float4*)(C + (size_t)(m0 + ty * 4 + i) * G4 + g0) = o;
        }
    }
}

// ---------------------------------------------------------------------------
// LSTM recurrence v4: LDS weights, wave-level k-split, quad-shuffle gates.
// 896 threads (14 waves): waves 0-6 kh=0 (k 0..52, owns xg), waves 7-13
// kh=1 (k 52..100, tail covered by h zero-pad). Within a wave:
// q = lane&3 (gate), u = w*16 + (lane>>2) (unit), row = q*100+u (act u<100).
// h reads are WAVE-UNIFORM ds_read_b128 (pure broadcast: kh fixed per wave
// -- fixes R11's 1e8 bank conflicts). Weight reads lane-varying, stride 400B
// -> conflict-free (R9/R10 measured 0). kh=1 writes partial to part[400];
// after barrier kh=0 adds, quad-gathers 4 gates via 3 shfl_xor (no LDS),
// computes (c,h) redundantly in the quad, q==0 writes h. 2 barriers/step.
// 14 waves = 3.5/SIMD hides ds latency (R10's 8-wave version was exposed).
// MODE 0: rot+tr fused (512 blocks); fc(H->3) on wave-6 idle lanes
// overlapped with matvec. MODE 1: write h seq. MODE 2: mean+fc+softmax.
// ---------------------------------------------------------------------------
template<int MODE>
__global__ __launch_bounds__(NW) void lstm_rec(
    const float* __restrict__ xgA, const float* __restrict__ xgB,
    const float* __restrict__ WhhA, const float* __restrict__ WhhB,
    const float* __restrict__ fwA, const float* __restrict__ fbA,
    const float* __restrict__ fwB, const float* __restrict__ fbB,
    float* __restrict__ oA, float* __restrict__ oB)
{
    __shared__ float wlds[G4 * HH + 4];   // 160,016 B (+pad: row399/kh1 tail)
    __shared__ float h_lds[104];          // h + zero pad [100..104)
    __shared__ float part[G4];            // kh=1 partials
    __shared__ float fcw[304];            // MODE0 fc weights+bias

    const int tid = threadIdx.x;
    int n = blockIdx.x;
    const float* xg = xgA;
    const float* whh = WhhA;
    const float* fw = fwA;
    const float* fb = fbA;
    float* op = oA;
    if (MODE == 0 && blockIdx.x >= NB) {
        n = blockIdx.x - NB;
        xg = xgB; whh = WhhB; fw = fwB; fb = fbB; op = oB;
    }

    // ---- stage Whh into LDS
    {
        const float4* src = (const float4*)whh;
        float4* dst = (float4*)wlds;
        for (int i = tid; i < G4 * HH / 4; i += NW) dst[i] = src[i];
    }
    if (tid < 4) wlds[G4 * HH + tid] = 0.f;
    if (tid < 104) h_lds[tid] = 0.f;
    if (MODE == 0) {
        for (int i = tid; i < 3 * HH; i += NW) fcw[i] = fw[i];
        if (tid < 4) fcw[3 * HH + tid] = (tid < 3) ? fb[tid] : 0.f;
    }
    __syncthreads();

    const int wave = tid >> 6, lane = tid & 63;
    const int kh = (wave >= 7) ? 1 : 0;
    const int w7 = kh ? wave - 7 : wave;
    const int q = lane & 3;
    const int u = w7 * 16 + (lane >> 2);
    const bool act = (u < HH);
    const int row = q * HH + (act ? u : 0);
    const int k0 = kh * 52;
    const float4* wrow = (const float4*)(wlds + row * HH + k0);
    const float4* hseg = (const float4*)(h_lds + k0);   // wave-uniform addr

    const bool isx = act && (kh == 0);
    const float* xgn = xg + (size_t)n * TT * G4 + row;
    float x0 = 0.f, x1 = 0.f;
    if (isx) { x0 = xgn[0]; x1 = xgn[G4]; }
    float c = 0.f, hsum = 0.f;

    const bool fcth = (MODE == 0) && (wave == 6) && (lane >= 32); // 32 idle lanes
    const int fcl = lane - 32;

    for (int t = 0; t < TT; ++t) {
        // MODE0: fc of h_{t-1} on idle lanes, overlapped with matvec
        // (h_lds stable until the post-B1 write of h_t).
        if (fcth && t > 0) {
            float p0 = 0.f, p1 = 0.f, p2 = 0.f;
            for (int k = fcl; k < HH; k += 32) {
                float hk = h_lds[k];
                p0 += hk * fcw[k];
                p1 += hk * fcw[HH + k];
                p2 += hk * fcw[2 * HH + k];
            }
#pragma unroll
            for (int s = 16; s; s >>= 1) {
                p0 += shflx(p0, s); p1 += shflx(p1, s); p2 += shflx(p2, s);
            }
            if (fcl == 0) {
                size_t o = ((size_t)n * TT + (t - 1)) * 3;
                op[o] = p0 + fcw[300];
                op[o + 1] = p1 + fcw[301];
                op[o + 2] = p2 + fcw[302];
            }
        }

        float gate = 0.f;
        if (act) {
            float s0 = isx ? x0 : 0.f;
            float s1 = 0.f, s2 = 0.f, s3 = 0.f;
            x0 = x1;
            if (isx && t + 2 < TT) x1 = xgn[(size_t)(t + 2) * G4];

            // opaque zero: keep weight ds_reads inside the loop (R5/R7 lesson)
            int z = t;
            asm volatile("" : "+v"(z));
            const float4* wrt = wrow + (z - t);
#pragma unroll
            for (int j = 0; j < 13; ++j) {
                float4 wv = wrt[j];
                float4 hv = hseg[j];   // broadcast; kh=1 j=12 hits zero pad
                switch (j & 3) {
                case 0: s0 = fmaf(hv.x, wv.x, fmaf(hv.y, wv.y, fmaf(hv.z, wv.z, fmaf(hv.w, wv.w, s0)))); break;
                case 1: s1 = fmaf(hv.x, wv.x, fmaf(hv.y, wv.y, fmaf(hv.z, wv.z, fmaf(hv.w, wv.w, s1)))); break;
                case 2: s2 = fmaf(hv.x, wv.x, fmaf(hv.y, wv.y, fmaf(hv.z, wv.z, fmaf(hv.w, wv.w, s2)))); break;
                default: s3 = fmaf(hv.x, wv.x, fmaf(hv.y, wv.y, fmaf(hv.z, wv.z, fmaf(hv.w, wv.w, s3)))); break;
                }
            }
            float s = (s0 + s1) + (s2 + s3);
            if (kh) part[row] = s;
            else gate = s;
        }
        __syncthreads();   // B1: partials visible

        if (act && kh == 0) {
            gate = gate + part[row];
            float g1  = shflx(gate, 1);
            float g2v = shflx(gate, 2);
            float g3  = shflx(g1, 2);
            float gi = (q == 0) ? gate : (q == 1) ? g1 : (q == 2) ? g2v : g3;
            float gf = (q == 1) ? gate : (q == 0) ? g1 : (q == 3) ? g2v : g3;
            float gg = (q == 2) ? gate : (q == 3) ? g1 : (q == 0) ? g2v : g3;
            float go = (q == 3) ? gate : (q == 2) ? g1 : (q == 1) ? g2v : g3;

            c = sigf(gf) * c + sigf(gi) * tanh_fast(gg);
            float h = sigf(go) * tanh_fast(c);
            if (q == 0) {
                h_lds[u] = h;
                if (MODE == 1) op[((size_t)n * TT + t) * HH + u] = h;
                if (MODE == 2) hsum += h;
            }
        }
        __syncthreads();   // B2: h_t visible
    }

    if (fcth) {
        // fc of the final h_{TT-1}
        float p0 = 0.f, p1 = 0.f, p2 = 0.f;
        for (int k = fcl; k < HH; k += 32) {
            float hk = h_lds[k];
            p0 += hk * fcw[k];
            p1 += hk * fcw[HH + k];
            p2 += hk * fcw[2 * HH + k];
        }
#pragma unroll
        for (int s = 16; s; s >>= 1) {
            p0 += shflx(p0, s); p1 += shflx(p1, s); p2 += shflx(p2, s);
        }
        if (fcl == 0) {
            size_t o = ((size_t)n * TT + (TT - 1)) * 3;
            op[o] = p0 + fcw[300];
            op[o + 1] = p1 + fcw[301];
            op[o + 2] = p2 + fcw[302];
        }
    }

    if (MODE == 2) {
        if (act && kh == 0 && q == 0) h_lds[u] = hsum * (1.f / TT);
        __syncthreads();
        if (tid < 64) {
            float logit = -3.0e38f;
            if (tid < NCLS) {
                float a = fb[tid];          // fc weights from global (L2-hot)
                const float* fr = fw + tid * HH;
#pragma unroll 10
                for (int k = 0; k < HH; ++k) a += h_lds[k] * fr[k];
                logit = a;
            }
            float mx = logit;
#pragma unroll
            for (int s = 32; s; s >>= 1) mx = fmaxf(mx, shflx(mx, s));
            float e = (tid < NCLS) ? __expf(logit - mx) : 0.f;
            float sum = e;
#pragma unroll
            for (int s = 32; s; s >>= 1) sum += shflx(sum, s);
            if (tid < NCLS) op[(size_t)n * NCLS + tid] = e / sum;
        }
    }
}

// ---------------------------------------------------------------------------
// Rotation/translation transform (unchanged)
// ---------------------------------------------------------------------------
__global__ __launch_bounds__(256) void transform_pts(
    const float* __restrict__ x, const float* __restrict__ rot,
    const float* __restrict__ tr, float* __restrict__ xr)
{
    const int idx = blockIdx.x * 4 + (threadIdx.x >> 6);
    const int lane = threadIdx.x & 63;
    const float* ang = rot + (size_t)idx * 3;
    float a = ang[0], b = ang[1], cg = ang[2];
    float ca = cosf(a), sa = sinf(a);
    float cb = cosf(b), sb = sinf(b);
    float cc = cosf(cg), sc = sinf(cg);
    float R00 = cc * cb, R01 = cc * sb * sa + sc * ca, R02 = -cc * sb * ca + sc * sa;
    float R10 = -sc * cb, R11 = -sc * sb * sa + cc * ca, R12 = sc * sb * ca + cc * sa;
    float R20 = sb, R21 = -cb * sa, R22 = cb * ca;
    float t0 = tr[(size_t)idx * 3], t1 = tr[(size_t)idx * 3 + 1], t2 = tr[(size_t)idx * 3 + 2];
    if (lane < 50) {
        const float* xp = x + (size_t)idx * SS + lane * 3;
        float p0 = xp[0] - t0, p1 = xp[1] - t1, p2 = xp[2] - t2;
        float* o = xr + (size_t)idx * SS + lane * 3;
        o[0] = R00 * p0 + R01 * p1 + R02 * p2;
        o[1] = R10 * p0 + R11 * p1 + R12 * p2;
        o[2] = R20 * p0 + R21 * p1 + R22 * p2;
    }
}

// ---------------------------------------------------------------------------
extern "C" void kernel_launch(void* const* d_in, const int* in_sizes, int n_in,
                              void* d_out, int out_size, void* d_ws, size_t ws_size,
                              hipStream_t stream)
{
    const float* x       = (const float*)d_in[0];
    const float* rot_Wih = (const float*)d_in[1];
    const float* rot_Whh = (const float*)d_in[2];
    const float* rot_bih = (const float*)d_in[3];
    const float* rot_bhh = (const float*)d_in[4];
    const float* tr_Wih  = (const float*)d_in[5];
    const float* tr_Whh  = (const float*)d_in[6];
    const float* tr_bih  = (const float*)d_in[7];
    const float* tr_bhh  = (const float*)d_in[8];
    const float* rot_fcW = (const float*)d_in[9];
    const float* rot_fcb = (const float*)d_in[10];
    const float* tr_fcW  = (const float*)d_in[11];
    const float* tr_fcb  = (const float*)d_in[12];
    const float* W0 = (const float*)d_in[13];
    const float* U0 = (const float*)d_in[14];
    const float* b0i = (const float*)d_in[15];
    const float* b0h = (const float*)d_in[16];
    const float* W1 = (const float*)d_in[17];
    const float* U1 = (const float*)d_in[18];
    const float* b1i = (const float*)d_in[19];
    const float* b1h = (const float*)d_in[20];
    const float* W2 = (const float*)d_in[21];
    const float* U2 = (const float*)d_in[22];
    const float* b2i = (const float*)d_in[23];
    const float* b2h = (const float*)d_in[24];
    const float* fcW = (const float*)d_in[25];
    const float* fcb = (const float*)d_in[26];
    float* out = (float*)d_out;

    float* ws = (float*)d_ws;
    float* xgA  = ws;
    float* xgB  = ws + 30720000ull;
    float* rotA = ws + 61440000ull;
    float* trO  = ws + 61670400ull;
    float* xr = xgA;
    float* h0 = xgA + 11520000ull;
    float* h1 = xgA + 19200000ull;

    dim3 gg(1200, 7), bb(256);
    gemm_inproj<150><<<gg, bb, 0, stream>>>(x, rot_Wih, rot_bih, rot_bhh, xgA);
    gemm_inproj<150><<<gg, bb, 0, stream>>>(x, tr_Wih, tr_bih, tr_bhh, xgB);
    lstm_rec<0><<<512, NW, 0, stream>>>(xgA, xgB, rot_Whh, tr_Whh,
                                        rot_fcW, rot_fcb, tr_fcW, tr_fcb,
                                        rotA, trO);
    transform_pts<<<19200, 256, 0, stream>>>(x, rotA, trO, xr);
    gemm_inproj<150><<<gg, bb, 0, stream>>>(xr, W0, b0i, b0h, xgB);
    lstm_rec<1><<<256, NW, 0, stream>>>(xgB, nullptr, U0, nullptr,
                                        nullptr, nullptr, nullptr, nullptr,
                                        h0, nullptr);
    gemm_inproj<100><<<gg, bb, 0, stream>>>(h0, W1, b1i, b1h, xgB);
    lstm_rec<1><<<256, NW, 0, stream>>>(xgB, nullptr, U1, nullptr,
                                        nullptr, nullptr, nullptr, nullptr,
                                        h1, nullptr);
    gemm_inproj<100><<<gg, bb, 0, stream>>>(h1, W2, b2i, b2h, xgB);
    lstm_rec<2><<<256, NW, 0, stream>>>(xgB, nullptr, U2, nullptr,
                                        fcW, fcb, nullptr, nullptr,
                                        out, nullptr);
}